// Round 1
// baseline (749.414 us; speedup 1.0000x reference)
//
#include <hip/hip_runtime.h>
#include <cstdint>
#include <cstddef>

#define D 128
#define NEG_SLOPE 0.2f

__device__ __forceinline__ float lrelu(float x) { return x > 0.0f ? x : NEG_SLOPE * x; }
__device__ __forceinline__ float elu_f(float x) { return x > 0.0f ? x : expm1f(x); }

// ---------------- GEMM: C[R x 128] = A[R x 128] @ W[128 x 128] + bias ----------------
// 256 threads/block, 64 rows/block, full 128 cols. Each thread: 4 rows x 8 cols.
__global__ __launch_bounds__(256) void gemm128(const float* __restrict__ A,
                                               const float* __restrict__ W,
                                               const float* __restrict__ bias,
                                               float* __restrict__ C, int R)
{
    __shared__ float As[64][33];    // [row][k_local], +1 pad breaks bank conflicts
    __shared__ float Ws[32][128];   // [k_local][col]
    const int tid = threadIdx.x;
    const int row0 = blockIdx.x * 64;
    const int cr = tid & 15;   // 16 col groups: cols {cr*4..cr*4+3} and {64+cr*4..}
    const int rr = tid >> 4;   // 16 row groups of 4 rows

    float acc[4][8];
#pragma unroll
    for (int i = 0; i < 4; ++i)
#pragma unroll
        for (int j = 0; j < 8; ++j) acc[i][j] = 0.0f;

    for (int kc = 0; kc < 128; kc += 32) {
        // stage A chunk: 64 rows x 32 k  (2 float4 per thread)
#pragma unroll
        for (int q = 0; q < 2; ++q) {
            int f = tid * 2 + q;
            int r = f >> 3, kq = f & 7;
            int gr = row0 + r; if (gr > R - 1) gr = R - 1;   // clamp (dup last row)
            const float4 a = *(const float4*)(A + (size_t)gr * D + kc + kq * 4);
            As[r][kq * 4 + 0] = a.x; As[r][kq * 4 + 1] = a.y;
            As[r][kq * 4 + 2] = a.z; As[r][kq * 4 + 3] = a.w;
        }
        // stage W chunk: 32 k x 128 cols (4 float4 per thread, coalesced)
#pragma unroll
        for (int q = 0; q < 4; ++q) {
            int f = tid + q * 256;
            int k = f >> 5, c4 = f & 31;
            *(float4*)&Ws[k][c4 * 4] = *(const float4*)(W + (size_t)(kc + k) * D + c4 * 4);
        }
        __syncthreads();
#pragma unroll
        for (int k = 0; k < 32; ++k) {
            float a0 = As[rr * 4 + 0][k];
            float a1 = As[rr * 4 + 1][k];
            float a2 = As[rr * 4 + 2][k];
            float a3 = As[rr * 4 + 3][k];
            float4 w0 = *(const float4*)&Ws[k][cr * 4];
            float4 w1 = *(const float4*)&Ws[k][64 + cr * 4];
            acc[0][0] += a0 * w0.x; acc[0][1] += a0 * w0.y; acc[0][2] += a0 * w0.z; acc[0][3] += a0 * w0.w;
            acc[0][4] += a0 * w1.x; acc[0][5] += a0 * w1.y; acc[0][6] += a0 * w1.z; acc[0][7] += a0 * w1.w;
            acc[1][0] += a1 * w0.x; acc[1][1] += a1 * w0.y; acc[1][2] += a1 * w0.z; acc[1][3] += a1 * w0.w;
            acc[1][4] += a1 * w1.x; acc[1][5] += a1 * w1.y; acc[1][6] += a1 * w1.z; acc[1][7] += a1 * w1.w;
            acc[2][0] += a2 * w0.x; acc[2][1] += a2 * w0.y; acc[2][2] += a2 * w0.z; acc[2][3] += a2 * w0.w;
            acc[2][4] += a2 * w1.x; acc[2][5] += a2 * w1.y; acc[2][6] += a2 * w1.z; acc[2][7] += a2 * w1.w;
            acc[3][0] += a3 * w0.x; acc[3][1] += a3 * w0.y; acc[3][2] += a3 * w0.z; acc[3][3] += a3 * w0.w;
            acc[3][4] += a3 * w1.x; acc[3][5] += a3 * w1.y; acc[3][6] += a3 * w1.z; acc[3][7] += a3 * w1.w;
        }
        __syncthreads();
    }

    float4 b0 = *(const float4*)(bias + cr * 4);
    float4 b1 = *(const float4*)(bias + 64 + cr * 4);
#pragma unroll
    for (int i = 0; i < 4; ++i) {
        int row = row0 + rr * 4 + i;
        if (row < R) {
            float4 o0 = make_float4(acc[i][0] + b0.x, acc[i][1] + b0.y, acc[i][2] + b0.z, acc[i][3] + b0.w);
            float4 o1 = make_float4(acc[i][4] + b1.x, acc[i][5] + b1.y, acc[i][6] + b1.z, acc[i][7] + b1.w);
            *(float4*)(C + (size_t)row * D + cr * 4) = o0;
            *(float4*)(C + (size_t)row * D + 64 + cr * 4) = o1;
        }
    }
}

// ---------------- per-node attention scalars: att[node] = (C·v0, C·v1, C·v2, C·v3) ----------------
__global__ __launch_bounds__(256) void att_scalars(const float* __restrict__ C,
                                                   const float* __restrict__ v0,
                                                   const float* __restrict__ v1,
                                                   const float* __restrict__ v2,
                                                   const float* __restrict__ v3,
                                                   float4* __restrict__ att, int R)
{
    int node = blockIdx.x * 4 + (threadIdx.x >> 6);
    int lane = threadIdx.x & 63;
    if (node >= R) return;
    const float* c = C + (size_t)node * D;
    float c0 = c[lane], c1 = c[64 + lane];
    float p0 = c0 * v0[lane] + c1 * v0[64 + lane];
    float p1 = c0 * v1[lane] + c1 * v1[64 + lane];
    float p2 = c0 * v2[lane] + c1 * v2[64 + lane];
    float p3 = c0 * v3[lane] + c1 * v3[64 + lane];
#pragma unroll
    for (int o = 32; o > 0; o >>= 1) {
        p0 += __shfl_xor(p0, o, 64);
        p1 += __shfl_xor(p1, o, 64);
        p2 += __shfl_xor(p2, o, 64);
        p3 += __shfl_xor(p3, o, 64);
    }
    if (lane == 0) att[node] = make_float4(p0, p1, p2, p3);
}

// ---------------- CSR build ----------------
__global__ void hist_kernel(const int* __restrict__ row, int* __restrict__ counts, int E)
{
    int i = blockIdx.x * blockDim.x + threadIdx.x;
    int stride = gridDim.x * blockDim.x;
    for (; i < E; i += stride) atomicAdd(&counts[row[i]], 1);
}

__global__ __launch_bounds__(256) void scan1(const int* __restrict__ counts,
                                             int* __restrict__ offsets,
                                             int* __restrict__ blockSums, int S)
{
    __shared__ int s[256];
    int tid = threadIdx.x;
    int i = blockIdx.x * 256 + tid;
    int v = (i < S) ? counts[i] : 0;
    s[tid] = v;
    __syncthreads();
    for (int o = 1; o < 256; o <<= 1) {
        int t = (tid >= o) ? s[tid - o] : 0;
        __syncthreads();
        s[tid] += t;
        __syncthreads();
    }
    if (i < S) offsets[i + 1] = s[tid];
    if (tid == 255) blockSums[blockIdx.x] = s[255];
}

__global__ __launch_bounds__(512) void scan2(int* __restrict__ sums, int nb)
{
    __shared__ int s[512];
    int tid = threadIdx.x;
    int v = (tid < nb) ? sums[tid] : 0;
    s[tid] = v;
    __syncthreads();
    for (int o = 1; o < 512; o <<= 1) {
        int t = (tid >= o) ? s[tid - o] : 0;
        __syncthreads();
        s[tid] += t;
        __syncthreads();
    }
    if (tid < nb) sums[tid] = s[tid] - v;   // exclusive
}

__global__ __launch_bounds__(256) void scan3(const int* __restrict__ counts,
                                             int* __restrict__ offsets,
                                             int* __restrict__ cursor,
                                             const int* __restrict__ blockSums, int S)
{
    int i = blockIdx.x * 256 + threadIdx.x;
    if (i >= S) return;
    int incl = offsets[i + 1] + blockSums[blockIdx.x];
    offsets[i + 1] = incl;
    cursor[i] = incl - counts[i];
    if (i == 0) offsets[0] = 0;
}

// ---------------- edge scatter: exp(leaky(logit)) into CSR order ----------------
// soff/doff select which half of the node float4 holds this direction's scalars.
__global__ void scatter_kernel(const int* __restrict__ row, const int* __restrict__ col,
                               const float4* __restrict__ satt, const float4* __restrict__ datt,
                               int soff, int doff, int* __restrict__ cursor,
                               int* __restrict__ scol, float* __restrict__ e0,
                               float* __restrict__ e1, int E)
{
    int i = blockIdx.x * blockDim.x + threadIdx.x;
    int stride = gridDim.x * blockDim.x;
    for (; i < E; i += stride) {
        int r = row[i], c = col[i];
        float4 s4 = satt[r];
        float4 d4 = datt[c];
        float sa0 = soff ? s4.z : s4.x;
        float sa1 = soff ? s4.w : s4.y;
        float da0 = doff ? d4.z : d4.x;
        float da1 = doff ? d4.w : d4.y;
        float l0 = lrelu(sa0 + da0);
        float l1 = lrelu(sa1 + da1);
        int pos = atomicAdd(&cursor[r], 1);
        scol[pos] = c;
        e0[pos] = __expf(l0);
        e1[pos] = __expf(l1);
    }
}

// ---------------- per-row aggregation: softmax denom + weighted gather + head-mean + ELU ----------------
__global__ __launch_bounds__(256) void aggregate_kernel(const int* __restrict__ offsets,
                                                        const int* __restrict__ scol,
                                                        const float* __restrict__ e0,
                                                        const float* __restrict__ e1,
                                                        const float* __restrict__ feat,
                                                        float* __restrict__ out, int S)
{
    int seg = blockIdx.x * 4 + (threadIdx.x >> 6);
    int lane = threadIdx.x & 63;
    if (seg >= S) return;
    int beg = offsets[seg], end = offsets[seg + 1];
    float s0 = 0.0f, s1 = 0.0f;
    for (int p = beg + lane; p < end; p += 64) { s0 += e0[p]; s1 += e1[p]; }
#pragma unroll
    for (int o = 32; o > 0; o >>= 1) {
        s0 += __shfl_xor(s0, o, 64);
        s1 += __shfl_xor(s1, o, 64);
    }
    float acc0 = 0.0f, acc1 = 0.0f;
    if (end > beg) {
        float inv0 = 0.5f / s0, inv1 = 0.5f / s1;   // 0.5 = mean over H=2 heads
        for (int p = beg; p < end; ++p) {
            float w = e0[p] * inv0 + e1[p] * inv1;
            const float* f = feat + (size_t)scol[p] * D;
            acc0 += w * f[lane];
            acc1 += w * f[64 + lane];
        }
    }
    out[(size_t)seg * D + lane] = elu_f(acc0);
    out[(size_t)seg * D + 64 + lane] = elu_f(acc1);
}

extern "C" void kernel_launch(void* const* d_in, const int* in_sizes, int n_in,
                              void* d_out, int out_size, void* d_ws, size_t ws_size,
                              hipStream_t stream)
{
    const float* u_prev  = (const float*)d_in[0];
    const float* i_prev  = (const float*)d_in[1];
    const float* w_user  = (const float*)d_in[2];
    const float* b_user  = (const float*)d_in[3];
    const float* w_item  = (const float*)d_in[4];
    const float* b_item  = (const float*)d_in[5];
    const float* a_u_src = (const float*)d_in[6];
    const float* a_u_dst = (const float*)d_in[7];
    const float* a_i_src = (const float*)d_in[8];
    const float* a_i_dst = (const float*)d_in[9];
    const int* u2i_row = (const int*)d_in[10];
    const int* u2i_col = (const int*)d_in[11];
    const int* i2u_row = (const int*)d_in[12];
    const int* i2u_col = (const int*)d_in[13];

    const int M = in_sizes[0] / D;
    const int N = in_sizes[1] / D;
    const int E = in_sizes[10];

    char* ws = (char*)d_ws;
    size_t off = 0;
    auto carve = [&](size_t bytes) -> char* {
        char* p = ws + off;
        off += (bytes + 255) & ~(size_t)255;
        return p;
    };
    float*  u_feat   = (float*)carve((size_t)M * D * 4);
    float*  i_feat   = (float*)carve((size_t)N * D * 4);
    float4* u_att    = (float4*)carve((size_t)M * 16);
    float4* i_att    = (float4*)carve((size_t)N * 16);
    int*    countsA  = (int*)carve((size_t)M * 4);
    int*    offsetsA = (int*)carve((size_t)(M + 1) * 4);
    int*    cursorA  = (int*)carve((size_t)M * 4);
    int*    bsumsA   = (int*)carve(512 * 4);
    int*    scolA    = (int*)carve((size_t)E * 4);
    float*  e0A      = (float*)carve((size_t)E * 4);
    float*  e1A      = (float*)carve((size_t)E * 4);
    int*    countsB  = (int*)carve((size_t)N * 4);
    int*    offsetsB = (int*)carve((size_t)(N + 1) * 4);
    int*    cursorB  = (int*)carve((size_t)N * 4);
    int*    bsumsB   = (int*)carve(512 * 4);
    int*    scolB    = (int*)carve((size_t)E * 4);
    float*  e0B      = (float*)carve((size_t)E * 4);
    float*  e1B      = (float*)carve((size_t)E * 4);
    (void)ws_size; (void)n_in; (void)out_size;

    hipMemsetAsync(countsA, 0, (size_t)M * 4, stream);
    hipMemsetAsync(countsB, 0, (size_t)N * 4, stream);

    // node transforms
    gemm128<<<(M + 63) / 64, 256, 0, stream>>>(u_prev, w_user, b_user, u_feat, M);
    gemm128<<<(N + 63) / 64, 256, 0, stream>>>(i_prev, w_item, b_item, i_feat, N);

    // per-node attention scalars:
    // u_att = (u·a_u_src0, u·a_u_src1, u·a_i_dst0, u·a_i_dst1)
    // i_att = (i·a_u_dst0, i·a_u_dst1, i·a_i_src0, i·a_i_src1)
    att_scalars<<<(M + 3) / 4, 256, 0, stream>>>(u_feat, a_u_src, a_u_src + D, a_i_dst, a_i_dst + D, u_att, M);
    att_scalars<<<(N + 3) / 4, 256, 0, stream>>>(i_feat, a_u_dst, a_u_dst + D, a_i_src, a_i_src + D, i_att, N);

    // CSR build per direction
    hist_kernel<<<1024, 256, 0, stream>>>(u2i_row, countsA, E);
    hist_kernel<<<1024, 256, 0, stream>>>(i2u_row, countsB, E);

    int nbA = (M + 255) / 256, nbB = (N + 255) / 256;
    scan1<<<nbA, 256, 0, stream>>>(countsA, offsetsA, bsumsA, M);
    scan1<<<nbB, 256, 0, stream>>>(countsB, offsetsB, bsumsB, N);
    scan2<<<1, 512, 0, stream>>>(bsumsA, nbA);
    scan2<<<1, 512, 0, stream>>>(bsumsB, nbB);
    scan3<<<nbA, 256, 0, stream>>>(countsA, offsetsA, cursorA, bsumsA, M);
    scan3<<<nbB, 256, 0, stream>>>(countsB, offsetsB, cursorB, bsumsB, N);

    // edge exp(leaky(logits)) into CSR slots (softmax max-subtraction skipped:
    // logits are O(5), exp is safe, softmax value is mathematically identical)
    scatter_kernel<<<1024, 256, 0, stream>>>(u2i_row, u2i_col, u_att, i_att, 0, 0,
                                             cursorA, scolA, e0A, e1A, E);
    scatter_kernel<<<1024, 256, 0, stream>>>(i2u_row, i2u_col, i_att, u_att, 2, 2,
                                             cursorB, scolB, e0B, e1B, E);

    // fused denom + weighted neighbor aggregation + head-mean + ELU, one wave per row
    float* out_u = (float*)d_out;
    float* out_i = out_u + (size_t)M * D;
    aggregate_kernel<<<(M + 3) / 4, 256, 0, stream>>>(offsetsA, scolA, e0A, e1A, i_feat, out_u, M);
    aggregate_kernel<<<(N + 3) / 4, 256, 0, stream>>>(offsetsB, scolB, e0B, e1B, u_feat, out_i, N);
}

// Round 2
// 565.087 us; speedup vs baseline: 1.3262x; 1.3262x over previous
//
#include <hip/hip_runtime.h>
#include <cstdint>
#include <cstddef>

#define D 128
#define NEG_SLOPE 0.2f

__device__ __forceinline__ float lrelu(float x) { return x > 0.0f ? x : NEG_SLOPE * x; }
__device__ __forceinline__ float elu_f(float x) { return x > 0.0f ? x : expm1f(x); }

// ---------------- GEMM + fused per-node attention scalars ----------------
// C[R x 128] = A[R x 128] @ W[128 x 128] + bias ; att[r] = (C[r]·v0, C[r]·v1, C[r]·v2, C[r]·v3)
struct GemmDir {
    const float* A; const float* W; const float* bias;
    const float* v0; const float* v1; const float* v2; const float* v3;
    float* C; float4* att; int R;
};

__global__ __launch_bounds__(256) void gemm_att(GemmDir g0, int nb0, GemmDir g1)
{
    const bool second = blockIdx.x >= nb0;
    GemmDir g = second ? g1 : g0;
    const int bid = second ? (blockIdx.x - nb0) : blockIdx.x;

    __shared__ float As[64][33];    // +1 pad breaks bank conflicts
    __shared__ float Ws[32][128];
    const int tid = threadIdx.x;
    const int row0 = bid * 64;
    const int cr = tid & 15;   // col group: cols {cr*4..+3} and {64+cr*4..+3}
    const int rr = tid >> 4;   // row group of 4 rows

    float acc[4][8];
#pragma unroll
    for (int i = 0; i < 4; ++i)
#pragma unroll
        for (int j = 0; j < 8; ++j) acc[i][j] = 0.0f;

    for (int kc = 0; kc < 128; kc += 32) {
#pragma unroll
        for (int q = 0; q < 2; ++q) {
            int f = tid * 2 + q;
            int r = f >> 3, kq = f & 7;
            int gr = row0 + r; if (gr > g.R - 1) gr = g.R - 1;   // clamp (dup last row)
            const float4 a = *(const float4*)(g.A + (size_t)gr * D + kc + kq * 4);
            As[r][kq * 4 + 0] = a.x; As[r][kq * 4 + 1] = a.y;
            As[r][kq * 4 + 2] = a.z; As[r][kq * 4 + 3] = a.w;
        }
#pragma unroll
        for (int q = 0; q < 4; ++q) {
            int f = tid + q * 256;
            int k = f >> 5, c4 = f & 31;
            *(float4*)&Ws[k][c4 * 4] = *(const float4*)(g.W + (size_t)(kc + k) * D + c4 * 4);
        }
        __syncthreads();
#pragma unroll
        for (int k = 0; k < 32; ++k) {
            float a0 = As[rr * 4 + 0][k];
            float a1 = As[rr * 4 + 1][k];
            float a2 = As[rr * 4 + 2][k];
            float a3 = As[rr * 4 + 3][k];
            float4 w0 = *(const float4*)&Ws[k][cr * 4];
            float4 w1 = *(const float4*)&Ws[k][64 + cr * 4];
            acc[0][0] += a0 * w0.x; acc[0][1] += a0 * w0.y; acc[0][2] += a0 * w0.z; acc[0][3] += a0 * w0.w;
            acc[0][4] += a0 * w1.x; acc[0][5] += a0 * w1.y; acc[0][6] += a0 * w1.z; acc[0][7] += a0 * w1.w;
            acc[1][0] += a1 * w0.x; acc[1][1] += a1 * w0.y; acc[1][2] += a1 * w0.z; acc[1][3] += a1 * w0.w;
            acc[1][4] += a1 * w1.x; acc[1][5] += a1 * w1.y; acc[1][6] += a1 * w1.z; acc[1][7] += a1 * w1.w;
            acc[2][0] += a2 * w0.x; acc[2][1] += a2 * w0.y; acc[2][2] += a2 * w0.z; acc[2][3] += a2 * w0.w;
            acc[2][4] += a2 * w1.x; acc[2][5] += a2 * w1.y; acc[2][6] += a2 * w1.z; acc[2][7] += a2 * w1.w;
            acc[3][0] += a3 * w0.x; acc[3][1] += a3 * w0.y; acc[3][2] += a3 * w0.z; acc[3][3] += a3 * w0.w;
            acc[3][4] += a3 * w1.x; acc[3][5] += a3 * w1.y; acc[3][6] += a3 * w1.z; acc[3][7] += a3 * w1.w;
        }
        __syncthreads();
    }

    float4 b0 = *(const float4*)(g.bias + cr * 4);
    float4 b1 = *(const float4*)(g.bias + 64 + cr * 4);
    // bias-included values (attention uses biased features too)
#pragma unroll
    for (int i = 0; i < 4; ++i) {
        acc[i][0] += b0.x; acc[i][1] += b0.y; acc[i][2] += b0.z; acc[i][3] += b0.w;
        acc[i][4] += b1.x; acc[i][5] += b1.y; acc[i][6] += b1.z; acc[i][7] += b1.w;
    }
#pragma unroll
    for (int i = 0; i < 4; ++i) {
        int row = row0 + rr * 4 + i;
        if (row < g.R) {
            *(float4*)(g.C + (size_t)row * D + cr * 4) =
                make_float4(acc[i][0], acc[i][1], acc[i][2], acc[i][3]);
            *(float4*)(g.C + (size_t)row * D + 64 + cr * 4) =
                make_float4(acc[i][4], acc[i][5], acc[i][6], acc[i][7]);
        }
    }

    // fused attention scalars: p[i][h] = C_row · v_h, reduced across the 16 col-group lanes
    const float* vs[4] = { g.v0, g.v1, g.v2, g.v3 };
    float p[4][4];
#pragma unroll
    for (int h = 0; h < 4; ++h) {
        float4 va = *(const float4*)(vs[h] + cr * 4);
        float4 vb = *(const float4*)(vs[h] + 64 + cr * 4);
#pragma unroll
        for (int i = 0; i < 4; ++i) {
            p[i][h] = acc[i][0] * va.x + acc[i][1] * va.y + acc[i][2] * va.z + acc[i][3] * va.w
                    + acc[i][4] * vb.x + acc[i][5] * vb.y + acc[i][6] * vb.z + acc[i][7] * vb.w;
        }
    }
#pragma unroll
    for (int i = 0; i < 4; ++i)
#pragma unroll
        for (int h = 0; h < 4; ++h)
#pragma unroll
            for (int o = 1; o < 16; o <<= 1)
                p[i][h] += __shfl_xor(p[i][h], o, 64);
    if (cr == 0) {
#pragma unroll
        for (int i = 0; i < 4; ++i) {
            int row = row0 + rr * 4 + i;
            if (row < g.R) g.att[row] = make_float4(p[i][0], p[i][1], p[i][2], p[i][3]);
        }
    }
}

// ---------------- CSR build: histogram (both directions, one launch) ----------------
__global__ __launch_bounds__(256) void hist2(const int* __restrict__ rowA, int* __restrict__ cntA, int EA,
                                             const int* __restrict__ rowB, int* __restrict__ cntB, int EB)
{
    int half = gridDim.x >> 1;
    bool dB = blockIdx.x >= half;
    const int* row = dB ? rowB : rowA;
    int* cnt = dB ? cntB : cntA;
    int E = dB ? EB : EA;
    int i = (dB ? blockIdx.x - half : blockIdx.x) * blockDim.x + threadIdx.x;
    int stride = half * blockDim.x;
    for (; i < E; i += stride) atomicAdd(&cnt[row[i]], 1);
}

// ---------------- scans ----------------
__device__ __forceinline__ void scan1_body(const int* counts, int* offsets, int* blockSums,
                                           int S, int bid)
{
    __shared__ int s[256];
    int tid = threadIdx.x;
    int i = bid * 256 + tid;
    int v = (i < S) ? counts[i] : 0;
    s[tid] = v;
    __syncthreads();
    for (int o = 1; o < 256; o <<= 1) {
        int t = (tid >= o) ? s[tid - o] : 0;
        __syncthreads();
        s[tid] += t;
        __syncthreads();
    }
    if (i < S) offsets[i + 1] = s[tid];
    if (tid == 255) blockSums[bid] = s[255];
}

__global__ __launch_bounds__(256) void scan1_both(const int* cA, int* offA, int* bsA, int SA, int nbA,
                                                  const int* cB, int* offB, int* bsB, int SB)
{
    if (blockIdx.x < (unsigned)nbA) scan1_body(cA, offA, bsA, SA, blockIdx.x);
    else scan1_body(cB, offB, bsB, SB, blockIdx.x - nbA);
}

__global__ __launch_bounds__(512) void scan2_both(int* sumsA, int nbA, int* sumsB, int nbB)
{
    int* sums = blockIdx.x ? sumsB : sumsA;
    int nb = blockIdx.x ? nbB : nbA;
    __shared__ int s[512];
    int tid = threadIdx.x;
    int v = (tid < nb) ? sums[tid] : 0;
    s[tid] = v;
    __syncthreads();
    for (int o = 1; o < 512; o <<= 1) {
        int t = (tid >= o) ? s[tid - o] : 0;
        __syncthreads();
        s[tid] += t;
        __syncthreads();
    }
    if (tid < nb) sums[tid] = s[tid] - v;   // exclusive
}

__device__ __forceinline__ void scan3_body(const int* counts, int* offsets, int* cursor,
                                           const int* blockSums, int S, int bid)
{
    int i = bid * 256 + threadIdx.x;
    if (i >= S) return;
    int incl = offsets[i + 1] + blockSums[bid];
    offsets[i + 1] = incl;
    cursor[i] = incl - counts[i];
    if (i == 0) offsets[0] = 0;
}

__global__ __launch_bounds__(256) void scan3_both(const int* cA, int* offA, int* curA, const int* bsA, int SA, int nbA,
                                                  const int* cB, int* offB, int* curB, const int* bsB, int SB)
{
    if (blockIdx.x < (unsigned)nbA) scan3_body(cA, offA, curA, bsA, SA, blockIdx.x);
    else scan3_body(cB, offB, curB, bsB, SB, blockIdx.x - nbA);
}

// ---------------- edge scatter: exp(leaky(logit)) into CSR order (both dirs) ----------------
// dir A uses (.x,.y) of node att float4s; dir B uses (.z,.w).
__global__ __launch_bounds__(256) void scatter_both(
    const int* __restrict__ rowA, const int* __restrict__ colA,
    const float4* __restrict__ sattA, const float4* __restrict__ dattA,
    int* __restrict__ curA, int* __restrict__ scolA, float2* __restrict__ eA, int EA,
    const int* __restrict__ rowB, const int* __restrict__ colB,
    const float4* __restrict__ sattB, const float4* __restrict__ dattB,
    int* __restrict__ curB, int* __restrict__ scolB, float2* __restrict__ eB, int EB)
{
    int half = gridDim.x >> 1;
    bool dB = blockIdx.x >= half;
    const int* row = dB ? rowB : rowA;
    const int* col = dB ? colB : colA;
    const float4* satt = dB ? sattB : sattA;
    const float4* datt = dB ? dattB : dattA;
    int* cursor = dB ? curB : curA;
    int* scol = dB ? scolB : scolA;
    float2* e01 = dB ? eB : eA;
    int E = dB ? EB : EA;

    int i = (dB ? blockIdx.x - half : blockIdx.x) * blockDim.x + threadIdx.x;
    int stride = half * blockDim.x;
    for (; i < E; i += stride) {
        int r = row[i], c = col[i];
        float4 s4 = satt[r];
        float4 d4 = datt[c];
        float sa0 = dB ? s4.z : s4.x;
        float sa1 = dB ? s4.w : s4.y;
        float da0 = dB ? d4.z : d4.x;
        float da1 = dB ? d4.w : d4.y;
        int pos = atomicAdd(&cursor[r], 1);
        scol[pos] = c;
        e01[pos] = make_float2(__expf(lrelu(sa0 + da0)), __expf(lrelu(sa1 + da1)));
    }
}

// ---------------- fused per-row softmax + aggregation + head-mean + ELU (both dirs) ----------------
// one wave per destination row; lanes split over D via float2 (512 B per edge in one request)
__device__ __forceinline__ void aggregate_row(const int* __restrict__ offsets,
                                              const int* __restrict__ scol,
                                              const float2* __restrict__ e01,
                                              const float* __restrict__ feat,
                                              float* __restrict__ out,
                                              int seg, int lane)
{
    int beg = offsets[seg], end = offsets[seg + 1];
    int deg = end - beg;
    float2 acc = make_float2(0.0f, 0.0f);
    if (deg > 0 && deg <= 64) {
        // preload this lane's edge metadata (one coalesced shot for the whole row)
        int myc = 0;
        float2 mye = make_float2(0.0f, 0.0f);
        if (lane < deg) { myc = scol[beg + lane]; mye = e01[beg + lane]; }
        float s0 = mye.x, s1 = mye.y;
#pragma unroll
        for (int o = 32; o > 0; o >>= 1) {
            s0 += __shfl_xor(s0, o, 64);
            s1 += __shfl_xor(s1, o, 64);
        }
        float myw = mye.x * (0.5f / s0) + mye.y * (0.5f / s1);  // 0.5 = head mean
        float2 a0 = make_float2(0.0f, 0.0f), a1 = a0, a2 = a0, a3 = a0;
        int j = 0;
        for (; j + 4 <= deg; j += 4) {
            int c0 = __shfl(myc, j, 64), c1 = __shfl(myc, j + 1, 64);
            int c2 = __shfl(myc, j + 2, 64), c3 = __shfl(myc, j + 3, 64);
            float w0 = __shfl(myw, j, 64), w1 = __shfl(myw, j + 1, 64);
            float w2 = __shfl(myw, j + 2, 64), w3 = __shfl(myw, j + 3, 64);
            float2 f0 = *(const float2*)(feat + (size_t)c0 * D + 2 * lane);
            float2 f1 = *(const float2*)(feat + (size_t)c1 * D + 2 * lane);
            float2 f2 = *(const float2*)(feat + (size_t)c2 * D + 2 * lane);
            float2 f3 = *(const float2*)(feat + (size_t)c3 * D + 2 * lane);
            a0.x += w0 * f0.x; a0.y += w0 * f0.y;
            a1.x += w1 * f1.x; a1.y += w1 * f1.y;
            a2.x += w2 * f2.x; a2.y += w2 * f2.y;
            a3.x += w3 * f3.x; a3.y += w3 * f3.y;
        }
        for (; j < deg; ++j) {
            int c0 = __shfl(myc, j, 64);
            float w0 = __shfl(myw, j, 64);
            float2 f0 = *(const float2*)(feat + (size_t)c0 * D + 2 * lane);
            a0.x += w0 * f0.x; a0.y += w0 * f0.y;
        }
        acc.x = (a0.x + a1.x) + (a2.x + a3.x);
        acc.y = (a0.y + a1.y) + (a2.y + a3.y);
    } else if (deg > 64) {
        // generic fallback (vanishingly rare for random graphs)
        float s0 = 0.0f, s1 = 0.0f;
        for (int p = beg + lane; p < end; p += 64) { float2 e = e01[p]; s0 += e.x; s1 += e.y; }
#pragma unroll
        for (int o = 32; o > 0; o >>= 1) {
            s0 += __shfl_xor(s0, o, 64);
            s1 += __shfl_xor(s1, o, 64);
        }
        float inv0 = 0.5f / s0, inv1 = 0.5f / s1;
        for (int p = beg; p < end; ++p) {
            float2 e = e01[p];
            float w = e.x * inv0 + e.y * inv1;
            float2 f = *(const float2*)(feat + (size_t)scol[p] * D + 2 * lane);
            acc.x += w * f.x; acc.y += w * f.y;
        }
    }
    *(float2*)(out + (size_t)seg * D + 2 * lane) = make_float2(elu_f(acc.x), elu_f(acc.y));
}

__global__ __launch_bounds__(256) void aggregate_both(
    const int* offA, const int* scolA, const float2* eA, const float* featA, float* outA, int SA, int nbA,
    const int* offB, const int* scolB, const float2* eB, const float* featB, float* outB, int SB)
{
    int lane = threadIdx.x & 63;
    if (blockIdx.x < (unsigned)nbA) {
        int seg = blockIdx.x * 4 + (threadIdx.x >> 6);
        if (seg < SA) aggregate_row(offA, scolA, eA, featA, outA, seg, lane);
    } else {
        int seg = (blockIdx.x - nbA) * 4 + (threadIdx.x >> 6);
        if (seg < SB) aggregate_row(offB, scolB, eB, featB, outB, seg, lane);
    }
}

extern "C" void kernel_launch(void* const* d_in, const int* in_sizes, int n_in,
                              void* d_out, int out_size, void* d_ws, size_t ws_size,
                              hipStream_t stream)
{
    const float* u_prev  = (const float*)d_in[0];
    const float* i_prev  = (const float*)d_in[1];
    const float* w_user  = (const float*)d_in[2];
    const float* b_user  = (const float*)d_in[3];
    const float* w_item  = (const float*)d_in[4];
    const float* b_item  = (const float*)d_in[5];
    const float* a_u_src = (const float*)d_in[6];
    const float* a_u_dst = (const float*)d_in[7];
    const float* a_i_src = (const float*)d_in[8];
    const float* a_i_dst = (const float*)d_in[9];
    const int* u2i_row = (const int*)d_in[10];
    const int* u2i_col = (const int*)d_in[11];
    const int* i2u_row = (const int*)d_in[12];
    const int* i2u_col = (const int*)d_in[13];

    const int M = in_sizes[0] / D;
    const int N = in_sizes[1] / D;
    const int EA = in_sizes[10];
    const int EB = in_sizes[12];

    char* ws = (char*)d_ws;
    size_t off = 0;
    auto carve = [&](size_t bytes) -> char* {
        char* p = ws + off;
        off += (bytes + 255) & ~(size_t)255;
        return p;
    };
    float*  u_feat   = (float*)carve((size_t)M * D * 4);
    float*  i_feat   = (float*)carve((size_t)N * D * 4);
    float4* u_att    = (float4*)carve((size_t)M * 16);
    float4* i_att    = (float4*)carve((size_t)N * 16);
    int*    countsA  = (int*)carve((size_t)M * 4);
    int*    offsetsA = (int*)carve((size_t)(M + 1) * 4);
    int*    cursorA  = (int*)carve((size_t)M * 4);
    int*    bsumsA   = (int*)carve(512 * 4);
    int*    scolA    = (int*)carve((size_t)EA * 4);
    float2* eA       = (float2*)carve((size_t)EA * 8);
    int*    countsB  = (int*)carve((size_t)N * 4);
    int*    offsetsB = (int*)carve((size_t)(N + 1) * 4);
    int*    cursorB  = (int*)carve((size_t)N * 4);
    int*    bsumsB   = (int*)carve(512 * 4);
    int*    scolB    = (int*)carve((size_t)EB * 4);
    float2* eB       = (float2*)carve((size_t)EB * 8);
    (void)ws_size; (void)n_in; (void)out_size;

    hipMemsetAsync(countsA, 0, (size_t)M * 4, stream);
    hipMemsetAsync(countsB, 0, (size_t)N * 4, stream);

    // node transforms + fused attention scalars
    // u_att = (u·a_u_src0, u·a_u_src1, u·a_i_dst0, u·a_i_dst1)
    // i_att = (i·a_u_dst0, i·a_u_dst1, i·a_i_src0, i·a_i_src1)
    GemmDir gu = { u_prev, w_user, b_user, a_u_src, a_u_src + D, a_i_dst, a_i_dst + D, u_feat, u_att, M };
    GemmDir gi = { i_prev, w_item, b_item, a_u_dst, a_u_dst + D, a_i_src, a_i_src + D, i_feat, i_att, N };
    int nbGu = (M + 63) / 64, nbGi = (N + 63) / 64;
    gemm_att<<<nbGu + nbGi, 256, 0, stream>>>(gu, nbGu, gi);

    // CSR build (both directions per launch)
    hist2<<<2048, 256, 0, stream>>>(u2i_row, countsA, EA, i2u_row, countsB, EB);

    int nbA = (M + 255) / 256, nbB = (N + 255) / 256;
    scan1_both<<<nbA + nbB, 256, 0, stream>>>(countsA, offsetsA, bsumsA, M, nbA,
                                              countsB, offsetsB, bsumsB, N);
    scan2_both<<<2, 512, 0, stream>>>(bsumsA, nbA, bsumsB, nbB);
    scan3_both<<<nbA + nbB, 256, 0, stream>>>(countsA, offsetsA, cursorA, bsumsA, M, nbA,
                                              countsB, offsetsB, cursorB, bsumsB, N);

    // per-edge exp(leaky(logits)) into CSR slots (softmax max-subtraction skipped:
    // logits are O(3), exp safe, softmax value mathematically identical)
    scatter_both<<<2048, 256, 0, stream>>>(u2i_row, u2i_col, u_att, i_att, cursorA, scolA, eA, EA,
                                           i2u_row, i2u_col, i_att, u_att, cursorB, scolB, eB, EB);

    // fused softmax denom + weighted aggregation + head-mean + ELU
    float* out_u = (float*)d_out;
    float* out_i = out_u + (size_t)M * D;
    int nbAggA = (M + 3) / 4, nbAggB = (N + 3) / 4;
    aggregate_both<<<nbAggA + nbAggB, 256, 0, stream>>>(offsetsA, scolA, eA, i_feat, out_u, M, nbAggA,
                                                        offsetsB, scolB, eB, u_feat, out_i, N);
}

// Round 3
// 560.340 us; speedup vs baseline: 1.3374x; 1.0085x over previous
//
#include <hip/hip_runtime.h>
#include <cstdint>
#include <cstddef>

#define D 128
#define NEG_SLOPE 0.2f

__device__ __forceinline__ float lrelu(float x) { return x > 0.0f ? x : NEG_SLOPE * x; }
__device__ __forceinline__ float elu_f(float x) { return x > 0.0f ? x : expm1f(x); }
__device__ __forceinline__ unsigned short f2bf(float f) {
    unsigned u = __float_as_uint(f);
    return (unsigned short)((u + 0x7fffu + ((u >> 16) & 1u)) >> 16);   // RNE
}

// ---------------- GEMM (+att scalars fused) + histogram (fused, hist blocks first) ----------------
// features are stored ONLY as bf16 (aggregation reads them at half traffic);
// attention scalars are computed from the fp32 accumulators (full precision).
struct GemmDir {
    const float* A; const float* W; const float* bias;
    const float* v0; const float* v1; const float* v2; const float* v3;
    unsigned short* Cb;   // bf16 features, row stride 128
    float4* att; int R;
};

__global__ __launch_bounds__(256) void gemm_att_hist(
    GemmDir g0, int nb0, GemmDir g1, int nbG,
    const int* __restrict__ rowA, int* __restrict__ cntA, int EA,
    const int* __restrict__ rowB, int* __restrict__ cntB, int EB, int histHalf)
{
    // hist blocks occupy the FRONT of the grid so they dispatch early and
    // finish under the gemm blocks' compute.
    int nbHist = 2 * histHalf;
    if ((int)blockIdx.x < nbHist) {
        bool dB = (int)blockIdx.x >= histHalf;
        const int* row = dB ? rowB : rowA;
        int* cnt = dB ? cntB : cntA;
        int E = dB ? EB : EA;
        int i = (dB ? blockIdx.x - histHalf : blockIdx.x) * 256 + threadIdx.x;
        int stride = histHalf * 256;
        for (; i < E; i += stride) atomicAdd(&cnt[row[i]], 1);
        return;
    }
    int gb = blockIdx.x - nbHist;
    const bool second = gb >= nb0;
    GemmDir g = second ? g1 : g0;
    const int bid = second ? (gb - nb0) : gb;
    (void)nbG;

    __shared__ float As[64][33];    // +1 pad breaks bank conflicts
    __shared__ float Ws[32][128];
    const int tid = threadIdx.x;
    const int row0 = bid * 64;
    const int cr = tid & 15;   // col group: cols {cr*4..+3} and {64+cr*4..+3}
    const int rr = tid >> 4;   // row group of 4 rows

    float acc[4][8];
#pragma unroll
    for (int i = 0; i < 4; ++i)
#pragma unroll
        for (int j = 0; j < 8; ++j) acc[i][j] = 0.0f;

    for (int kc = 0; kc < 128; kc += 32) {
#pragma unroll
        for (int q = 0; q < 2; ++q) {
            int f = tid * 2 + q;
            int r = f >> 3, kq = f & 7;
            int gr = row0 + r; if (gr > g.R - 1) gr = g.R - 1;   // clamp (dup last row)
            const float4 a = *(const float4*)(g.A + (size_t)gr * D + kc + kq * 4);
            As[r][kq * 4 + 0] = a.x; As[r][kq * 4 + 1] = a.y;
            As[r][kq * 4 + 2] = a.z; As[r][kq * 4 + 3] = a.w;
        }
#pragma unroll
        for (int q = 0; q < 4; ++q) {
            int f = tid + q * 256;
            int k = f >> 5, c4 = f & 31;
            *(float4*)&Ws[k][c4 * 4] = *(const float4*)(g.W + (size_t)(kc + k) * D + c4 * 4);
        }
        __syncthreads();
#pragma unroll
        for (int k = 0; k < 32; ++k) {
            float a0 = As[rr * 4 + 0][k];
            float a1 = As[rr * 4 + 1][k];
            float a2 = As[rr * 4 + 2][k];
            float a3 = As[rr * 4 + 3][k];
            float4 w0 = *(const float4*)&Ws[k][cr * 4];
            float4 w1 = *(const float4*)&Ws[k][64 + cr * 4];
            acc[0][0] += a0 * w0.x; acc[0][1] += a0 * w0.y; acc[0][2] += a0 * w0.z; acc[0][3] += a0 * w0.w;
            acc[0][4] += a0 * w1.x; acc[0][5] += a0 * w1.y; acc[0][6] += a0 * w1.z; acc[0][7] += a0 * w1.w;
            acc[1][0] += a1 * w0.x; acc[1][1] += a1 * w0.y; acc[1][2] += a1 * w0.z; acc[1][3] += a1 * w0.w;
            acc[1][4] += a1 * w1.x; acc[1][5] += a1 * w1.y; acc[1][6] += a1 * w1.z; acc[1][7] += a1 * w1.w;
            acc[2][0] += a2 * w0.x; acc[2][1] += a2 * w0.y; acc[2][2] += a2 * w0.z; acc[2][3] += a2 * w0.w;
            acc[2][4] += a2 * w1.x; acc[2][5] += a2 * w1.y; acc[2][6] += a2 * w1.z; acc[2][7] += a2 * w1.w;
            acc[3][0] += a3 * w0.x; acc[3][1] += a3 * w0.y; acc[3][2] += a3 * w0.z; acc[3][3] += a3 * w0.w;
            acc[3][4] += a3 * w1.x; acc[3][5] += a3 * w1.y; acc[3][6] += a3 * w1.z; acc[3][7] += a3 * w1.w;
        }
        __syncthreads();
    }

    float4 b0 = *(const float4*)(g.bias + cr * 4);
    float4 b1 = *(const float4*)(g.bias + 64 + cr * 4);
#pragma unroll
    for (int i = 0; i < 4; ++i) {
        acc[i][0] += b0.x; acc[i][1] += b0.y; acc[i][2] += b0.z; acc[i][3] += b0.w;
        acc[i][4] += b1.x; acc[i][5] += b1.y; acc[i][6] += b1.z; acc[i][7] += b1.w;
    }
    // bf16 feature store (only consumer is the aggregation gather)
#pragma unroll
    for (int i = 0; i < 4; ++i) {
        int row = row0 + rr * 4 + i;
        if (row < g.R) {
            ushort4 s0 = { f2bf(acc[i][0]), f2bf(acc[i][1]), f2bf(acc[i][2]), f2bf(acc[i][3]) };
            ushort4 s1 = { f2bf(acc[i][4]), f2bf(acc[i][5]), f2bf(acc[i][6]), f2bf(acc[i][7]) };
            *(ushort4*)(g.Cb + (size_t)row * D + cr * 4) = s0;
            *(ushort4*)(g.Cb + (size_t)row * D + 64 + cr * 4) = s1;
        }
    }

    // fused attention scalars from fp32 accs: p[i][h] = C_row · v_h
    const float* vs[4] = { g.v0, g.v1, g.v2, g.v3 };
    float p[4][4];
#pragma unroll
    for (int h = 0; h < 4; ++h) {
        float4 va = *(const float4*)(vs[h] + cr * 4);
        float4 vb = *(const float4*)(vs[h] + 64 + cr * 4);
#pragma unroll
        for (int i = 0; i < 4; ++i) {
            p[i][h] = acc[i][0] * va.x + acc[i][1] * va.y + acc[i][2] * va.z + acc[i][3] * va.w
                    + acc[i][4] * vb.x + acc[i][5] * vb.y + acc[i][6] * vb.z + acc[i][7] * vb.w;
        }
    }
#pragma unroll
    for (int i = 0; i < 4; ++i)
#pragma unroll
        for (int h = 0; h < 4; ++h)
#pragma unroll
            for (int o = 1; o < 16; o <<= 1)
                p[i][h] += __shfl_xor(p[i][h], o, 64);
    if (cr == 0) {
#pragma unroll
        for (int i = 0; i < 4; ++i) {
            int row = row0 + rr * 4 + i;
            if (row < g.R) g.att[row] = make_float4(p[i][0], p[i][1], p[i][2], p[i][3]);
        }
    }
}

// ---------------- scans ----------------
__device__ __forceinline__ void scan1_body(const int* counts, int* offsets, int* blockSums,
                                           int S, int bid)
{
    __shared__ int s[256];
    int tid = threadIdx.x;
    int i = bid * 256 + tid;
    int v = (i < S) ? counts[i] : 0;
    s[tid] = v;
    __syncthreads();
    for (int o = 1; o < 256; o <<= 1) {
        int t = (tid >= o) ? s[tid - o] : 0;
        __syncthreads();
        s[tid] += t;
        __syncthreads();
    }
    if (i < S) offsets[i + 1] = s[tid];
    if (tid == 255) blockSums[bid] = s[255];
}

__global__ __launch_bounds__(256) void scan1_both(const int* cA, int* offA, int* bsA, int SA, int nbA,
                                                  const int* cB, int* offB, int* bsB, int SB)
{
    if (blockIdx.x < (unsigned)nbA) scan1_body(cA, offA, bsA, SA, blockIdx.x);
    else scan1_body(cB, offB, bsB, SB, blockIdx.x - nbA);
}

__global__ __launch_bounds__(512) void scan2_both(int* sumsA, int nbA, int* sumsB, int nbB)
{
    int* sums = blockIdx.x ? sumsB : sumsA;
    int nb = blockIdx.x ? nbB : nbA;
    __shared__ int s[512];
    int tid = threadIdx.x;
    int v = (tid < nb) ? sums[tid] : 0;
    s[tid] = v;
    __syncthreads();
    for (int o = 1; o < 512; o <<= 1) {
        int t = (tid >= o) ? s[tid - o] : 0;
        __syncthreads();
        s[tid] += t;
        __syncthreads();
    }
    if (tid < nb) sums[tid] = s[tid] - v;   // exclusive
}

__device__ __forceinline__ void scan3_body(const int* counts, int* offsets, int* cursor,
                                           const int* blockSums, int S, int bid)
{
    int i = bid * 256 + threadIdx.x;
    if (i >= S) return;
    int incl = offsets[i + 1] + blockSums[bid];
    offsets[i + 1] = incl;
    cursor[i] = incl - counts[i];
    if (i == 0) offsets[0] = 0;
}

__global__ __launch_bounds__(256) void scan3_both(const int* cA, int* offA, int* curA, const int* bsA, int SA, int nbA,
                                                  const int* cB, int* offB, int* curB, const int* bsB, int SB)
{
    if (blockIdx.x < (unsigned)nbA) scan3_body(cA, offA, curA, bsA, SA, blockIdx.x);
    else scan3_body(cB, offB, curB, bsB, SB, blockIdx.x - nbA);
}

// ---------------- edge scatter: CSR column list only (exp moved into aggregate) ----------------
__global__ __launch_bounds__(256) void scatter_both(
    const int* __restrict__ rowA, const int* __restrict__ colA,
    int* __restrict__ curA, int* __restrict__ scolA, int EA,
    const int* __restrict__ rowB, const int* __restrict__ colB,
    int* __restrict__ curB, int* __restrict__ scolB, int EB)
{
    int half = gridDim.x >> 1;
    bool dB = blockIdx.x >= half;
    const int* row = dB ? rowB : rowA;
    const int* col = dB ? colB : colA;
    int* cursor = dB ? curB : curA;
    int* scol = dB ? scolB : scolA;
    int E = dB ? EB : EA;

    int i = (dB ? blockIdx.x - half : blockIdx.x) * 256 + threadIdx.x;
    int stride = half * 256;
    for (; i < E; i += stride) {
        int r = row[i];
        int pos = atomicAdd(&cursor[r], 1);
        scol[pos] = col[i];
    }
}

// ---------------- fused exp(leaky) + softmax + aggregation + head-mean + ELU ----------------
// one wave per destination row. satt/datt are byte pointers pre-offset to this
// direction's head pair inside the node float4 (stride 16 B). feat is bf16.
__device__ __forceinline__ void aggregate_row(
    const int* __restrict__ offsets, const int* __restrict__ scol,
    const char* __restrict__ satt, const char* __restrict__ datt,
    const unsigned short* __restrict__ featb,
    float* __restrict__ out, int seg, int lane)
{
    int beg = offsets[seg], end = offsets[seg + 1];
    int deg = end - beg;
    float2 sa = *(const float2*)(satt + (size_t)seg * 16);   // wave-uniform broadcast
    float accx = 0.0f, accy = 0.0f;
    if (deg > 0 && deg <= 64) {
        int myc = 0;
        float e0 = 0.0f, e1 = 0.0f;
        if (lane < deg) {
            myc = scol[beg + lane];                          // coalesced
            float2 da = *(const float2*)(datt + (size_t)myc * 16);   // L2-resident gather
            e0 = __expf(lrelu(sa.x + da.x));
            e1 = __expf(lrelu(sa.y + da.y));
        }
        float s0 = e0, s1 = e1;
#pragma unroll
        for (int o = 32; o > 0; o >>= 1) {
            s0 += __shfl_xor(s0, o, 64);
            s1 += __shfl_xor(s1, o, 64);
        }
        float myw = e0 * (0.5f / s0) + e1 * (0.5f / s1);     // 0.5 = mean over H=2 heads
        float a0x = 0.f, a0y = 0.f, a1x = 0.f, a1y = 0.f,
              a2x = 0.f, a2y = 0.f, a3x = 0.f, a3y = 0.f;
        int j = 0;
        for (; j + 4 <= deg; j += 4) {
            int c0 = __shfl(myc, j, 64), c1 = __shfl(myc, j + 1, 64);
            int c2 = __shfl(myc, j + 2, 64), c3 = __shfl(myc, j + 3, 64);
            float w0 = __shfl(myw, j, 64), w1 = __shfl(myw, j + 1, 64);
            float w2 = __shfl(myw, j + 2, 64), w3 = __shfl(myw, j + 3, 64);
            unsigned f0 = *(const unsigned*)(featb + (size_t)c0 * D + 2 * lane);
            unsigned f1 = *(const unsigned*)(featb + (size_t)c1 * D + 2 * lane);
            unsigned f2 = *(const unsigned*)(featb + (size_t)c2 * D + 2 * lane);
            unsigned f3 = *(const unsigned*)(featb + (size_t)c3 * D + 2 * lane);
            a0x += w0 * __uint_as_float(f0 << 16); a0y += w0 * __uint_as_float(f0 & 0xffff0000u);
            a1x += w1 * __uint_as_float(f1 << 16); a1y += w1 * __uint_as_float(f1 & 0xffff0000u);
            a2x += w2 * __uint_as_float(f2 << 16); a2y += w2 * __uint_as_float(f2 & 0xffff0000u);
            a3x += w3 * __uint_as_float(f3 << 16); a3y += w3 * __uint_as_float(f3 & 0xffff0000u);
        }
        for (; j < deg; ++j) {
            int c0 = __shfl(myc, j, 64);
            float w0 = __shfl(myw, j, 64);
            unsigned f0 = *(const unsigned*)(featb + (size_t)c0 * D + 2 * lane);
            a0x += w0 * __uint_as_float(f0 << 16); a0y += w0 * __uint_as_float(f0 & 0xffff0000u);
        }
        accx = (a0x + a1x) + (a2x + a3x);
        accy = (a0y + a1y) + (a2y + a3y);
    } else if (deg > 64) {
        // generic fallback (P ~ 0 for Poisson(10/20) rows, correctness only)
        float s0 = 0.0f, s1 = 0.0f;
        for (int p = beg + lane; p < end; p += 64) {
            int c = scol[p];
            float2 da = *(const float2*)(datt + (size_t)c * 16);
            s0 += __expf(lrelu(sa.x + da.x));
            s1 += __expf(lrelu(sa.y + da.y));
        }
#pragma unroll
        for (int o = 32; o > 0; o >>= 1) {
            s0 += __shfl_xor(s0, o, 64);
            s1 += __shfl_xor(s1, o, 64);
        }
        float inv0 = 0.5f / s0, inv1 = 0.5f / s1;
        for (int p = beg; p < end; ++p) {
            int c = scol[p];
            float2 da = *(const float2*)(datt + (size_t)c * 16);
            float w = __expf(lrelu(sa.x + da.x)) * inv0 + __expf(lrelu(sa.y + da.y)) * inv1;
            unsigned f = *(const unsigned*)(featb + (size_t)c * D + 2 * lane);
            accx += w * __uint_as_float(f << 16);
            accy += w * __uint_as_float(f & 0xffff0000u);
        }
    }
    *(float2*)(out + (size_t)seg * D + 2 * lane) = make_float2(elu_f(accx), elu_f(accy));
}

__global__ __launch_bounds__(256) void aggregate_both(
    const int* offA, const int* scolA, const char* sattA, const char* dattA,
    const unsigned short* featA, float* outA, int SA, int nbA,
    const int* offB, const int* scolB, const char* sattB, const char* dattB,
    const unsigned short* featB, float* outB, int SB)
{
    int lane = threadIdx.x & 63;
    if (blockIdx.x < (unsigned)nbA) {
        int seg = blockIdx.x * 4 + (threadIdx.x >> 6);
        if (seg < SA) aggregate_row(offA, scolA, sattA, dattA, featA, outA, seg, lane);
    } else {
        int seg = (blockIdx.x - nbA) * 4 + (threadIdx.x >> 6);
        if (seg < SB) aggregate_row(offB, scolB, sattB, dattB, featB, outB, seg, lane);
    }
}

extern "C" void kernel_launch(void* const* d_in, const int* in_sizes, int n_in,
                              void* d_out, int out_size, void* d_ws, size_t ws_size,
                              hipStream_t stream)
{
    const float* u_prev  = (const float*)d_in[0];
    const float* i_prev  = (const float*)d_in[1];
    const float* w_user  = (const float*)d_in[2];
    const float* b_user  = (const float*)d_in[3];
    const float* w_item  = (const float*)d_in[4];
    const float* b_item  = (const float*)d_in[5];
    const float* a_u_src = (const float*)d_in[6];
    const float* a_u_dst = (const float*)d_in[7];
    const float* a_i_src = (const float*)d_in[8];
    const float* a_i_dst = (const float*)d_in[9];
    const int* u2i_row = (const int*)d_in[10];
    const int* u2i_col = (const int*)d_in[11];
    const int* i2u_row = (const int*)d_in[12];
    const int* i2u_col = (const int*)d_in[13];

    const int M = in_sizes[0] / D;
    const int N = in_sizes[1] / D;
    const int EA = in_sizes[10];
    const int EB = in_sizes[12];

    char* ws = (char*)d_ws;
    size_t off = 0;
    auto carve = [&](size_t bytes) -> char* {
        char* p = ws + off;
        off += (bytes + 255) & ~(size_t)255;
        return p;
    };
    unsigned short* u_featb = (unsigned short*)carve((size_t)M * D * 2);
    unsigned short* i_featb = (unsigned short*)carve((size_t)N * D * 2);
    float4* u_att    = (float4*)carve((size_t)M * 16);
    float4* i_att    = (float4*)carve((size_t)N * 16);
    int*    countsA  = (int*)carve((size_t)M * 4);
    int*    offsetsA = (int*)carve((size_t)(M + 1) * 4);
    int*    cursorA  = (int*)carve((size_t)M * 4);
    int*    bsumsA   = (int*)carve(512 * 4);
    int*    scolA    = (int*)carve((size_t)EA * 4);
    int*    countsB  = (int*)carve((size_t)N * 4);
    int*    offsetsB = (int*)carve((size_t)(N + 1) * 4);
    int*    cursorB  = (int*)carve((size_t)N * 4);
    int*    bsumsB   = (int*)carve(512 * 4);
    int*    scolB    = (int*)carve((size_t)EB * 4);
    (void)ws_size; (void)n_in; (void)out_size;

    hipMemsetAsync(countsA, 0, (size_t)M * 4, stream);
    hipMemsetAsync(countsB, 0, (size_t)N * 4, stream);

    // node transforms + fused attention scalars + (front-loaded) edge histograms
    // u_att = (u·a_u_src0, u·a_u_src1, u·a_i_dst0, u·a_i_dst1)
    // i_att = (i·a_u_dst0, i·a_u_dst1, i·a_i_src0, i·a_i_src1)
    GemmDir gu = { u_prev, w_user, b_user, a_u_src, a_u_src + D, a_i_dst, a_i_dst + D, u_featb, u_att, M };
    GemmDir gi = { i_prev, w_item, b_item, a_u_dst, a_u_dst + D, a_i_src, a_i_src + D, i_featb, i_att, N };
    int nbGu = (M + 63) / 64, nbGi = (N + 63) / 64;
    int histHalf = 512;
    gemm_att_hist<<<2 * histHalf + nbGu + nbGi, 256, 0, stream>>>(
        gu, nbGu, gi, nbGu + nbGi,
        u2i_row, countsA, EA, i2u_row, countsB, EB, histHalf);

    int nbA = (M + 255) / 256, nbB = (N + 255) / 256;
    scan1_both<<<nbA + nbB, 256, 0, stream>>>(countsA, offsetsA, bsumsA, M, nbA,
                                              countsB, offsetsB, bsumsB, N);
    scan2_both<<<2, 512, 0, stream>>>(bsumsA, nbA, bsumsB, nbB);
    scan3_both<<<nbA + nbB, 256, 0, stream>>>(countsA, offsetsA, cursorA, bsumsA, M, nbA,
                                              countsB, offsetsB, cursorB, bsumsB, N);

    // CSR column lists (one random 4 B write + one atomic per edge)
    scatter_both<<<1024, 256, 0, stream>>>(u2i_row, u2i_col, cursorA, scolA, EA,
                                           i2u_row, i2u_col, cursorB, scolB, EB);

    // fused exp(leaky) + softmax denom + weighted aggregation + head-mean + ELU
    // dir A: satt = u_att heads (.x,.y) -> offset 0 ; datt = i_att (.x,.y) -> offset 0
    // dir B: satt = i_att heads (.z,.w) -> offset 8 ; datt = u_att (.z,.w) -> offset 8
    float* out_u = (float*)d_out;
    float* out_i = out_u + (size_t)M * D;
    int nbAggA = (M + 3) / 4, nbAggB = (N + 3) / 4;
    aggregate_both<<<nbAggA + nbAggB, 256, 0, stream>>>(
        offsetsA, scolA, (const char*)u_att, (const char*)i_att, i_featb, out_u, M, nbAggA,
        offsetsB, scolB, (const char*)i_att + 8, (const char*)u_att + 8, u_featb, out_i, N);
}

// Round 4
// 473.796 us; speedup vs baseline: 1.5817x; 1.1827x over previous
//
#include <hip/hip_runtime.h>
#include <cstdint>
#include <cstddef>

#define D 128
#define NEG_SLOPE 0.2f

__device__ __forceinline__ float lrelu(float x) { return x > 0.0f ? x : NEG_SLOPE * x; }
__device__ __forceinline__ float elu_f(float x) { return x > 0.0f ? x : expm1f(x); }
__device__ __forceinline__ unsigned short f2bf(float f) {
    unsigned u = __float_as_uint(f);
    return (unsigned short)((u + 0x7fffu + ((u >> 16) & 1u)) >> 16);   // RNE
}

// ---------------- GEMM (+att scalars fused) + histogram (fused, hist blocks first) ----------------
// features are stored ONLY as bf16 (aggregation reads them at half traffic);
// attention scalars are computed from the fp32 accumulators (full precision).
struct GemmDir {
    const float* A; const float* W; const float* bias;
    const float* v0; const float* v1; const float* v2; const float* v3;
    unsigned short* Cb;   // bf16 features, row stride 128
    float4* att; int R;
};

__global__ __launch_bounds__(256) void gemm_att_hist(
    GemmDir g0, int nb0, GemmDir g1, int nbG,
    const int* __restrict__ rowA, int* __restrict__ cntA, int EA,
    const int* __restrict__ rowB, int* __restrict__ cntB, int EB, int histHalf)
{
    // hist blocks occupy the FRONT of the grid so they dispatch early and
    // finish under the gemm blocks' compute.
    int nbHist = 2 * histHalf;
    if ((int)blockIdx.x < nbHist) {
        bool dB = (int)blockIdx.x >= histHalf;
        const int* row = dB ? rowB : rowA;
        int* cnt = dB ? cntB : cntA;
        int E = dB ? EB : EA;
        int i = (dB ? blockIdx.x - histHalf : blockIdx.x) * 256 + threadIdx.x;
        int stride = histHalf * 256;
        for (; i < E; i += stride) atomicAdd(&cnt[row[i]], 1);
        return;
    }
    int gb = blockIdx.x - nbHist;
    const bool second = gb >= nb0;
    GemmDir g = second ? g1 : g0;
    const int bid = second ? (gb - nb0) : gb;
    (void)nbG;

    __shared__ float As[64][33];    // +1 pad breaks bank conflicts
    __shared__ float Ws[32][128];
    const int tid = threadIdx.x;
    const int row0 = bid * 64;
    const int cr = tid & 15;   // col group: cols {cr*4..+3} and {64+cr*4..+3}
    const int rr = tid >> 4;   // row group of 4 rows

    float acc[4][8];
#pragma unroll
    for (int i = 0; i < 4; ++i)
#pragma unroll
        for (int j = 0; j < 8; ++j) acc[i][j] = 0.0f;

    for (int kc = 0; kc < 128; kc += 32) {
#pragma unroll
        for (int q = 0; q < 2; ++q) {
            int f = tid * 2 + q;
            int r = f >> 3, kq = f & 7;
            int gr = row0 + r; if (gr > g.R - 1) gr = g.R - 1;   // clamp (dup last row)
            const float4 a = *(const float4*)(g.A + (size_t)gr * D + kc + kq * 4);
            As[r][kq * 4 + 0] = a.x; As[r][kq * 4 + 1] = a.y;
            As[r][kq * 4 + 2] = a.z; As[r][kq * 4 + 3] = a.w;
        }
#pragma unroll
        for (int q = 0; q < 4; ++q) {
            int f = tid + q * 256;
            int k = f >> 5, c4 = f & 31;
            *(float4*)&Ws[k][c4 * 4] = *(const float4*)(g.W + (size_t)(kc + k) * D + c4 * 4);
        }
        __syncthreads();
#pragma unroll
        for (int k = 0; k < 32; ++k) {
            float a0 = As[rr * 4 + 0][k];
            float a1 = As[rr * 4 + 1][k];
            float a2 = As[rr * 4 + 2][k];
            float a3 = As[rr * 4 + 3][k];
            float4 w0 = *(const float4*)&Ws[k][cr * 4];
            float4 w1 = *(const float4*)&Ws[k][64 + cr * 4];
            acc[0][0] += a0 * w0.x; acc[0][1] += a0 * w0.y; acc[0][2] += a0 * w0.z; acc[0][3] += a0 * w0.w;
            acc[0][4] += a0 * w1.x; acc[0][5] += a0 * w1.y; acc[0][6] += a0 * w1.z; acc[0][7] += a0 * w1.w;
            acc[1][0] += a1 * w0.x; acc[1][1] += a1 * w0.y; acc[1][2] += a1 * w0.z; acc[1][3] += a1 * w0.w;
            acc[1][4] += a1 * w1.x; acc[1][5] += a1 * w1.y; acc[1][6] += a1 * w1.z; acc[1][7] += a1 * w1.w;
            acc[2][0] += a2 * w0.x; acc[2][1] += a2 * w0.y; acc[2][2] += a2 * w0.z; acc[2][3] += a2 * w0.w;
            acc[2][4] += a2 * w1.x; acc[2][5] += a2 * w1.y; acc[2][6] += a2 * w1.z; acc[2][7] += a2 * w1.w;
            acc[3][0] += a3 * w0.x; acc[3][1] += a3 * w0.y; acc[3][2] += a3 * w0.z; acc[3][3] += a3 * w0.w;
            acc[3][4] += a3 * w1.x; acc[3][5] += a3 * w1.y; acc[3][6] += a3 * w1.z; acc[3][7] += a3 * w1.w;
        }
        __syncthreads();
    }

    float4 b0 = *(const float4*)(g.bias + cr * 4);
    float4 b1 = *(const float4*)(g.bias + 64 + cr * 4);
#pragma unroll
    for (int i = 0; i < 4; ++i) {
        acc[i][0] += b0.x; acc[i][1] += b0.y; acc[i][2] += b0.z; acc[i][3] += b0.w;
        acc[i][4] += b1.x; acc[i][5] += b1.y; acc[i][6] += b1.z; acc[i][7] += b1.w;
    }
    // bf16 feature store (only consumer is the aggregation gather)
#pragma unroll
    for (int i = 0; i < 4; ++i) {
        int row = row0 + rr * 4 + i;
        if (row < g.R) {
            ushort4 s0 = { f2bf(acc[i][0]), f2bf(acc[i][1]), f2bf(acc[i][2]), f2bf(acc[i][3]) };
            ushort4 s1 = { f2bf(acc[i][4]), f2bf(acc[i][5]), f2bf(acc[i][6]), f2bf(acc[i][7]) };
            *(ushort4*)(g.Cb + (size_t)row * D + cr * 4) = s0;
            *(ushort4*)(g.Cb + (size_t)row * D + 64 + cr * 4) = s1;
        }
    }

    // fused attention scalars from fp32 accs: p[i][h] = C_row · v_h
    const float* vs[4] = { g.v0, g.v1, g.v2, g.v3 };
    float p[4][4];
#pragma unroll
    for (int h = 0; h < 4; ++h) {
        float4 va = *(const float4*)(vs[h] + cr * 4);
        float4 vb = *(const float4*)(vs[h] + 64 + cr * 4);
#pragma unroll
        for (int i = 0; i < 4; ++i) {
            p[i][h] = acc[i][0] * va.x + acc[i][1] * va.y + acc[i][2] * va.z + acc[i][3] * va.w
                    + acc[i][4] * vb.x + acc[i][5] * vb.y + acc[i][6] * vb.z + acc[i][7] * vb.w;
        }
    }
#pragma unroll
    for (int i = 0; i < 4; ++i)
#pragma unroll
        for (int h = 0; h < 4; ++h)
#pragma unroll
            for (int o = 1; o < 16; o <<= 1)
                p[i][h] += __shfl_xor(p[i][h], o, 64);
    if (cr == 0) {
#pragma unroll
        for (int i = 0; i < 4; ++i) {
            int row = row0 + rr * 4 + i;
            if (row < g.R) g.att[row] = make_float4(p[i][0], p[i][1], p[i][2], p[i][3]);
        }
    }
}

// ---------------- scans ----------------
__device__ __forceinline__ void scan1_body(const int* counts, int* offsets, int* blockSums,
                                           int S, int bid)
{
    __shared__ int s[256];
    int tid = threadIdx.x;
    int i = bid * 256 + tid;
    int v = (i < S) ? counts[i] : 0;
    s[tid] = v;
    __syncthreads();
    for (int o = 1; o < 256; o <<= 1) {
        int t = (tid >= o) ? s[tid - o] : 0;
        __syncthreads();
        s[tid] += t;
        __syncthreads();
    }
    if (i < S) offsets[i + 1] = s[tid];
    if (tid == 255) blockSums[bid] = s[255];
}

__global__ __launch_bounds__(256) void scan1_both(const int* cA, int* offA, int* bsA, int SA, int nbA,
                                                  const int* cB, int* offB, int* bsB, int SB)
{
    if (blockIdx.x < (unsigned)nbA) scan1_body(cA, offA, bsA, SA, blockIdx.x);
    else scan1_body(cB, offB, bsB, SB, blockIdx.x - nbA);
}

__global__ __launch_bounds__(512) void scan2_both(int* sumsA, int nbA, int* sumsB, int nbB)
{
    int* sums = blockIdx.x ? sumsB : sumsA;
    int nb = blockIdx.x ? nbB : nbA;
    __shared__ int s[512];
    int tid = threadIdx.x;
    int v = (tid < nb) ? sums[tid] : 0;
    s[tid] = v;
    __syncthreads();
    for (int o = 1; o < 512; o <<= 1) {
        int t = (tid >= o) ? s[tid - o] : 0;
        __syncthreads();
        s[tid] += t;
        __syncthreads();
    }
    if (tid < nb) sums[tid] = s[tid] - v;   // exclusive
}

__device__ __forceinline__ void scan3_body(const int* counts, int* offsets, int* cursor,
                                           const int* blockSums, int S, int bid)
{
    int i = bid * 256 + threadIdx.x;
    if (i >= S) return;
    int incl = offsets[i + 1] + blockSums[bid];
    offsets[i + 1] = incl;
    cursor[i] = incl - counts[i];
    if (i == 0) offsets[0] = 0;
}

__global__ __launch_bounds__(256) void scan3_both(const int* cA, int* offA, int* curA, const int* bsA, int SA, int nbA,
                                                  const int* cB, int* offB, int* curB, const int* bsB, int SB)
{
    if (blockIdx.x < (unsigned)nbA) scan3_body(cA, offA, curA, bsA, SA, blockIdx.x);
    else scan3_body(cB, offB, curB, bsB, SB, blockIdx.x - nbA);
}

// ---------------- edge scatter: row-partitioned to kill cross-XCD line ping-pong ----------------
// Partition destination rows into 8 contiguous chunks; block b serves partition
// b&7 (matches round-robin block->XCD dispatch), so each CSR output region is
// written by blocks sharing one L2: 64B lines fill locally, write back ONCE.
// Cost: row[]/col[] scanned 8x (L2/L3-resident re-reads) -- cheap vs the 16x
// write amplification it removes (R3: WRITE_SIZE 130MB for 8MB of payload).
__global__ __launch_bounds__(256) void scatter_both(
    const int* __restrict__ rowA, const int* __restrict__ colA,
    int* __restrict__ curA, int* __restrict__ scolA, int EA, int chunkA,
    const int* __restrict__ rowB, const int* __restrict__ colB,
    int* __restrict__ curB, int* __restrict__ scolB, int EB, int chunkB)
{
    int half = gridDim.x >> 1;
    bool dB = (int)blockIdx.x >= half;
    int b = dB ? (int)blockIdx.x - half : (int)blockIdx.x;
    const int* row = dB ? rowB : rowA;
    const int* col = dB ? colB : colA;
    int* cursor = dB ? curB : curA;
    int* scol = dB ? scolB : scolA;
    int E = dB ? EB : EA;
    int chunk = dB ? chunkB : chunkA;

    int part = b & 7;          // ~XCD id under round-robin dispatch
    int idx  = b >> 3;         // block index within partition
    int nper = half >> 3;      // blocks per partition
    int lo = part * chunk, hi = lo + chunk;

    for (int i = idx * 256 + (int)threadIdx.x; i < E; i += nper * 256) {
        int r = row[i];
        if (r >= lo && r < hi) {
            int pos = atomicAdd(&cursor[r], 1);
            scol[pos] = col[i];
        }
    }
}

// ---------------- fused exp(leaky) + softmax + aggregation + head-mean + ELU ----------------
// one wave per destination row. satt/datt are byte pointers pre-offset to this
// direction's head pair inside the node float4 (stride 16 B). feat is bf16.
__device__ __forceinline__ void aggregate_row(
    const int* __restrict__ offsets, const int* __restrict__ scol,
    const char* __restrict__ satt, const char* __restrict__ datt,
    const unsigned short* __restrict__ featb,
    float* __restrict__ out, int seg, int lane)
{
    int beg = offsets[seg], end = offsets[seg + 1];
    int deg = end - beg;
    float2 sa = *(const float2*)(satt + (size_t)seg * 16);   // wave-uniform broadcast
    float accx = 0.0f, accy = 0.0f;
    if (deg > 0 && deg <= 64) {
        int myc = 0;
        float e0 = 0.0f, e1 = 0.0f;
        if (lane < deg) {
            myc = scol[beg + lane];                          // coalesced
            float2 da = *(const float2*)(datt + (size_t)myc * 16);   // L2-resident gather
            e0 = __expf(lrelu(sa.x + da.x));
            e1 = __expf(lrelu(sa.y + da.y));
        }
        float s0 = e0, s1 = e1;
#pragma unroll
        for (int o = 32; o > 0; o >>= 1) {
            s0 += __shfl_xor(s0, o, 64);
            s1 += __shfl_xor(s1, o, 64);
        }
        float myw = e0 * (0.5f / s0) + e1 * (0.5f / s1);     // 0.5 = mean over H=2 heads
        float a0x = 0.f, a0y = 0.f, a1x = 0.f, a1y = 0.f,
              a2x = 0.f, a2y = 0.f, a3x = 0.f, a3y = 0.f;
        int j = 0;
        for (; j + 4 <= deg; j += 4) {
            int c0 = __shfl(myc, j, 64), c1 = __shfl(myc, j + 1, 64);
            int c2 = __shfl(myc, j + 2, 64), c3 = __shfl(myc, j + 3, 64);
            float w0 = __shfl(myw, j, 64), w1 = __shfl(myw, j + 1, 64);
            float w2 = __shfl(myw, j + 2, 64), w3 = __shfl(myw, j + 3, 64);
            unsigned f0 = *(const unsigned*)(featb + (size_t)c0 * D + 2 * lane);
            unsigned f1 = *(const unsigned*)(featb + (size_t)c1 * D + 2 * lane);
            unsigned f2 = *(const unsigned*)(featb + (size_t)c2 * D + 2 * lane);
            unsigned f3 = *(const unsigned*)(featb + (size_t)c3 * D + 2 * lane);
            a0x += w0 * __uint_as_float(f0 << 16); a0y += w0 * __uint_as_float(f0 & 0xffff0000u);
            a1x += w1 * __uint_as_float(f1 << 16); a1y += w1 * __uint_as_float(f1 & 0xffff0000u);
            a2x += w2 * __uint_as_float(f2 << 16); a2y += w2 * __uint_as_float(f2 & 0xffff0000u);
            a3x += w3 * __uint_as_float(f3 << 16); a3y += w3 * __uint_as_float(f3 & 0xffff0000u);
        }
        for (; j < deg; ++j) {
            int c0 = __shfl(myc, j, 64);
            float w0 = __shfl(myw, j, 64);
            unsigned f0 = *(const unsigned*)(featb + (size_t)c0 * D + 2 * lane);
            a0x += w0 * __uint_as_float(f0 << 16); a0y += w0 * __uint_as_float(f0 & 0xffff0000u);
        }
        accx = (a0x + a1x) + (a2x + a3x);
        accy = (a0y + a1y) + (a2y + a3y);
    } else if (deg > 64) {
        // generic fallback (P ~ 0 for Poisson(10/20) rows, correctness only)
        float s0 = 0.0f, s1 = 0.0f;
        for (int p = beg + lane; p < end; p += 64) {
            int c = scol[p];
            float2 da = *(const float2*)(datt + (size_t)c * 16);
            s0 += __expf(lrelu(sa.x + da.x));
            s1 += __expf(lrelu(sa.y + da.y));
        }
#pragma unroll
        for (int o = 32; o > 0; o >>= 1) {
            s0 += __shfl_xor(s0, o, 64);
            s1 += __shfl_xor(s1, o, 64);
        }
        float inv0 = 0.5f / s0, inv1 = 0.5f / s1;
        for (int p = beg; p < end; ++p) {
            int c = scol[p];
            float2 da = *(const float2*)(datt + (size_t)c * 16);
            float w = __expf(lrelu(sa.x + da.x)) * inv0 + __expf(lrelu(sa.y + da.y)) * inv1;
            unsigned f = *(const unsigned*)(featb + (size_t)c * D + 2 * lane);
            accx += w * __uint_as_float(f << 16);
            accy += w * __uint_as_float(f & 0xffff0000u);
        }
    }
    *(float2*)(out + (size_t)seg * D + 2 * lane) = make_float2(elu_f(accx), elu_f(accy));
}

__global__ __launch_bounds__(256) void aggregate_both(
    const int* offA, const int* scolA, const char* sattA, const char* dattA,
    const unsigned short* featA, float* outA, int SA, int nbA,
    const int* offB, const int* scolB, const char* sattB, const char* dattB,
    const unsigned short* featB, float* outB, int SB)
{
    int lane = threadIdx.x & 63;
    if (blockIdx.x < (unsigned)nbA) {
        int seg = blockIdx.x * 4 + (threadIdx.x >> 6);
        if (seg < SA) aggregate_row(offA, scolA, sattA, dattA, featA, outA, seg, lane);
    } else {
        int seg = (blockIdx.x - nbA) * 4 + (threadIdx.x >> 6);
        if (seg < SB) aggregate_row(offB, scolB, sattB, dattB, featB, outB, seg, lane);
    }
}

extern "C" void kernel_launch(void* const* d_in, const int* in_sizes, int n_in,
                              void* d_out, int out_size, void* d_ws, size_t ws_size,
                              hipStream_t stream)
{
    const float* u_prev  = (const float*)d_in[0];
    const float* i_prev  = (const float*)d_in[1];
    const float* w_user  = (const float*)d_in[2];
    const float* b_user  = (const float*)d_in[3];
    const float* w_item  = (const float*)d_in[4];
    const float* b_item  = (const float*)d_in[5];
    const float* a_u_src = (const float*)d_in[6];
    const float* a_u_dst = (const float*)d_in[7];
    const float* a_i_src = (const float*)d_in[8];
    const float* a_i_dst = (const float*)d_in[9];
    const int* u2i_row = (const int*)d_in[10];
    const int* u2i_col = (const int*)d_in[11];
    const int* i2u_row = (const int*)d_in[12];
    const int* i2u_col = (const int*)d_in[13];

    const int M = in_sizes[0] / D;
    const int N = in_sizes[1] / D;
    const int EA = in_sizes[10];
    const int EB = in_sizes[12];

    char* ws = (char*)d_ws;
    size_t off = 0;
    auto carve = [&](size_t bytes) -> char* {
        char* p = ws + off;
        off += (bytes + 255) & ~(size_t)255;
        return p;
    };
    unsigned short* u_featb = (unsigned short*)carve((size_t)M * D * 2);
    unsigned short* i_featb = (unsigned short*)carve((size_t)N * D * 2);
    float4* u_att    = (float4*)carve((size_t)M * 16);
    float4* i_att    = (float4*)carve((size_t)N * 16);
    int*    countsA  = (int*)carve((size_t)M * 4);
    int*    offsetsA = (int*)carve((size_t)(M + 1) * 4);
    int*    cursorA  = (int*)carve((size_t)M * 4);
    int*    bsumsA   = (int*)carve(512 * 4);
    int*    scolA    = (int*)carve((size_t)EA * 4);
    int*    countsB  = (int*)carve((size_t)N * 4);
    int*    offsetsB = (int*)carve((size_t)(N + 1) * 4);
    int*    cursorB  = (int*)carve((size_t)N * 4);
    int*    bsumsB   = (int*)carve(512 * 4);
    int*    scolB    = (int*)carve((size_t)EB * 4);
    (void)ws_size; (void)n_in; (void)out_size;

    hipMemsetAsync(countsA, 0, (size_t)M * 4, stream);
    hipMemsetAsync(countsB, 0, (size_t)N * 4, stream);

    // node transforms + fused attention scalars + (front-loaded) edge histograms
    // u_att = (u·a_u_src0, u·a_u_src1, u·a_i_dst0, u·a_i_dst1)
    // i_att = (i·a_u_dst0, i·a_u_dst1, i·a_i_src0, i·a_i_src1)
    GemmDir gu = { u_prev, w_user, b_user, a_u_src, a_u_src + D, a_i_dst, a_i_dst + D, u_featb, u_att, M };
    GemmDir gi = { i_prev, w_item, b_item, a_u_dst, a_u_dst + D, a_i_src, a_i_src + D, i_featb, i_att, N };
    int nbGu = (M + 63) / 64, nbGi = (N + 63) / 64;
    int histHalf = 512;
    gemm_att_hist<<<2 * histHalf + nbGu + nbGi, 256, 0, stream>>>(
        gu, nbGu, gi, nbGu + nbGi,
        u2i_row, countsA, EA, i2u_row, countsB, EB, histHalf);

    int nbA = (M + 255) / 256, nbB = (N + 255) / 256;
    scan1_both<<<nbA + nbB, 256, 0, stream>>>(countsA, offsetsA, bsumsA, M, nbA,
                                              countsB, offsetsB, bsumsB, N);
    scan2_both<<<2, 512, 0, stream>>>(bsumsA, nbA, bsumsB, nbB);
    scan3_both<<<nbA + nbB, 256, 0, stream>>>(countsA, offsetsA, cursorA, bsumsA, M, nbA,
                                              countsB, offsetsB, cursorB, bsumsB, N);

    // row-partitioned CSR column scatter (see kernel comment)
    int chunkA = (M + 7) / 8, chunkB = (N + 7) / 8;
    scatter_both<<<2048, 256, 0, stream>>>(u2i_row, u2i_col, cursorA, scolA, EA, chunkA,
                                           i2u_row, i2u_col, cursorB, scolB, EB, chunkB);

    // fused exp(leaky) + softmax denom + weighted aggregation + head-mean + ELU
    // dir A: satt = u_att heads (.x,.y) -> offset 0 ; datt = i_att (.x,.y) -> offset 0
    // dir B: satt = i_att heads (.z,.w) -> offset 8 ; datt = u_att (.z,.w) -> offset 8
    float* out_u = (float*)d_out;
    float* out_i = out_u + (size_t)M * D;
    int nbAggA = (M + 3) / 4, nbAggB = (N + 3) / 4;
    aggregate_both<<<nbAggA + nbAggB, 256, 0, stream>>>(
        offsetsA, scolA, (const char*)u_att, (const char*)i_att, i_featb, out_u, M, nbAggA,
        offsetsB, scolB, (const char*)i_att + 8, (const char*)u_att + 8, u_featb, out_i, N);
}